// Round 6
// baseline (1581.430 us; speedup 1.0000x reference)
//
#include <hip/hip_runtime.h>
#include <hip/hip_bf16.h>
#include <stdint.h>

#define N_NODES 16384
#define GG      128
#define HD      64
#define MAXD    192
#define BN_EPS  1e-5f
#define NSLOT   16             // stats contention slots
#define STG     (NSLOT * 128)  // doubles per stats group (group stride!)

typedef unsigned short u16;
typedef unsigned int   u32;
typedef unsigned long long u64;
typedef u32 u32x4 __attribute__((ext_vector_type(4)));  // nontemporal-compatible

__device__ __forceinline__ float bf2f(u16 u) {
    union { u32 i; float f; } c; c.i = ((u32)u) << 16; return c.f;
}
// param load in native dtype (flag: 1=f32, 0=bf16)
__device__ __forceinline__ float ldp(const void* p, int i, int flag) {
    return flag ? ((const float*)p)[i] : bf2f(((const u16*)p)[i]);
}

// ---------------------------------------------------------------------------
// K1: LEAN fused scan+gather (R2 version — do NOT fatten this kernel: it must
// run at max occupancy to keep the nontemporal adj stream at the HBM floor).
//  phase 1: streaming ballot-compaction scan of adj row -> cols in LDS
//  phase 2: cols -> global (for K4's spmm), gather pooled -> P0
// Housekeeping: zero 4*STG stats arena, publish dtype flag from adj[0][0]
// (f32 -> word0 low16 == 0; bf16 -> low16 = 0x3F80 != 0).
__global__ __launch_bounds__(256) void k_scan_gather(
    const void* __restrict__ adjv, const void* __restrict__ xv,
    u16* __restrict__ cols, int* __restrict__ cnt,
    float* __restrict__ invdeg, float* __restrict__ pooled,
    double* __restrict__ statsD, int* __restrict__ flagp)
{
    __shared__ __align__(16) u16 sc[4][MAXD];
    const int wave = threadIdx.x >> 6, lane = threadIdx.x & 63;
    const int row = blockIdx.x * 4 + wave;
    const u32 w0 = *(const u32*)adjv;                      // scalar, cached
    const int flag = ((w0 & 0xFFFFu) == 0) ? 1 : 0;
    const u64 ltmask = ((1ull << lane) - 1ull);

    // housekeeping
    const int gid = blockIdx.x * 256 + threadIdx.x;
    if (gid < 4 * STG) statsD[gid] = 0.0;
    if (gid == 0) *flagp = flag;

    u16* __restrict__ srow = sc[wave];
    int base = 0;
    if (flag) {  // ---- f32: u32x4 = 4 elements, 256 elems/wave-chunk ----
        const u32x4* __restrict__ arow =
            (const u32x4*)((const u32*)adjv + (size_t)row * N_NODES) + lane;
        u32x4 p0 = __builtin_nontemporal_load(arow);
        u32x4 p1 = __builtin_nontemporal_load(arow + 64);
        for (int c = 0; c < N_NODES; c += 256) {
            u32x4 raw = p0;
            p0 = p1;
            if (c + 512 < N_NODES)
                p1 = __builtin_nontemporal_load(arow + (c + 512) / 4);
            #pragma unroll
            for (int e = 0; e < 4; ++e) {
                u32 w = raw[e];
                u64 m = __ballot(w != 0);
                if (m) {
                    if (w) {
                        int p = base + __popcll(m & ltmask);
                        if (p < MAXD) srow[p] = (u16)(c + lane * 4 + e);
                    }
                    base += __popcll(m);
                }
            }
        }
    } else {     // ---- bf16: u32x4 = 8 elements, 512 elems/wave-chunk ----
        const u32x4* __restrict__ arow =
            (const u32x4*)((const u16*)adjv + (size_t)row * N_NODES) + lane;
        u32x4 p0 = __builtin_nontemporal_load(arow);
        u32x4 p1 = __builtin_nontemporal_load(arow + 64);
        for (int c = 0; c < N_NODES; c += 512) {
            u32x4 raw = p0;
            p0 = p1;
            if (c + 1024 < N_NODES)
                p1 = __builtin_nontemporal_load(arow + (c + 1024) / 8);
            #pragma unroll
            for (int e = 0; e < 8; ++e) {
                u16 u = (u16)(raw[e >> 1] >> ((e & 1) * 16));
                u64 m = __ballot(u != 0);
                if (m) {
                    if (u) {
                        int p = base + __popcll(m & ltmask);
                        if (p < MAXD) srow[p] = (u16)(c + lane * 8 + e);
                    }
                    base += __popcll(m);
                }
            }
        }
    }
    const int n = (base < MAXD) ? base : MAXD;
    if (lane == 0) cnt[row] = n;
    __syncthreads();   // LDS cols visible

    // stream cols to global (garbage > n ok, reads bounded by cnt)
    {
        u32* __restrict__ crow32 = (u32*)(cols + (size_t)row * MAXD);
        const u32* __restrict__ s32 = (const u32*)srow;
        #pragma unroll
        for (int t = lane; t < MAXD / 2; t += 64) crow32[t] = s32[t];
    }

    // gather (cols from LDS are wave-uniform broadcasts)
    float acc = 0.f;
    int k = 0;
    if (flag) {
        const float* __restrict__ x = (const float*)xv;
        for (; k + 4 <= n; k += 4) {
            ushort4 j4 = *(const ushort4*)&srow[k];
            float v0 = x[(size_t)j4.x * HD + lane];
            float v1 = x[(size_t)j4.y * HD + lane];
            float v2 = x[(size_t)j4.z * HD + lane];
            float v3 = x[(size_t)j4.w * HD + lane];
            acc += (v0 + v1) + (v2 + v3);
        }
        for (; k < n; ++k) acc += x[(size_t)srow[k] * HD + lane];
    } else {
        const u16* __restrict__ x = (const u16*)xv;
        for (; k + 4 <= n; k += 4) {
            ushort4 j4 = *(const ushort4*)&srow[k];
            float v0 = bf2f(x[(size_t)j4.x * HD + lane]);
            float v1 = bf2f(x[(size_t)j4.y * HD + lane]);
            float v2 = bf2f(x[(size_t)j4.z * HD + lane]);
            float v3 = bf2f(x[(size_t)j4.w * HD + lane]);
            acc += (v0 + v1) + (v2 + v3);
        }
        for (; k < n; ++k) acc += bf2f(x[(size_t)srow[k] * HD + lane]);
    }
    float inv = 1.f / (float)n;                     // n >= 1 (self-loop)
    pooled[(size_t)row * HD + lane] = acc * inv;
    if (lane == 0) invdeg[row] = inv;
}

// ---------------------------------------------------------------------------
// K2/K3/K5: dst[N,64] = f(src)[N,64] @ W[64,64] + bias, + fused column stats.
// f = identity (AFFINE=false) or per-feature relu(A*v+C) (AFFINE=true) with
// A,C from the NSLOT-slot statsIn group. 16 rows/block (1024 blocks).
template<bool AFFINE>
__global__ __launch_bounds__(256) void k_mm(
    const float* __restrict__ src, const double* __restrict__ statsIn,
    const void* __restrict__ g, const void* __restrict__ be,
    const void* __restrict__ W, const void* __restrict__ bias,
    float* __restrict__ dst, double* __restrict__ statsOut,
    const int* __restrict__ flagp)
{
    __shared__ float Wf[64 * 64];
    __shared__ float S[16 * 64];
    __shared__ float ac[128];
    __shared__ double shs[256];
    __shared__ double shq[256];
    const int tid = threadIdx.x;
    const int flag = *flagp;
    if (AFFINE) {
        if (tid < 64) {
            double ss = 0.0, qq = 0.0;
            #pragma unroll
            for (int s2 = 0; s2 < NSLOT; ++s2) {
                ss += statsIn[s2 * 128 + tid];
                qq += statsIn[s2 * 128 + 64 + tid];
            }
            double m = ss * (1.0 / N_NODES);
            double v = qq * (1.0 / N_NODES) - m * m;
            float A = ldp(g, tid, flag) / sqrtf((float)v + BN_EPS);
            ac[tid] = A;
            ac[64 + tid] = ldp(be, tid, flag) - (float)m * A;
        }
        __syncthreads();
    }
    for (int i = tid; i < 64 * 64; i += 256) Wf[i] = ldp(W, i, flag);
    const int rbase = blockIdx.x * 16;
    {
        float4 v = *(const float4*)&src[(size_t)rbase * 64 + tid * 4];
        if (AFFINE) {
            const int f0 = (tid * 4) & 63;
            v.x = fmaxf(fmaf(ac[f0 + 0], v.x, ac[64 + f0 + 0]), 0.f);
            v.y = fmaxf(fmaf(ac[f0 + 1], v.y, ac[64 + f0 + 1]), 0.f);
            v.z = fmaxf(fmaf(ac[f0 + 2], v.z, ac[64 + f0 + 2]), 0.f);
            v.w = fmaxf(fmaf(ac[f0 + 3], v.w, ac[64 + f0 + 3]), 0.f);
        }
        *(float4*)&S[tid * 4] = v;
    }
    __syncthreads();
    const int f = tid & 63, r0 = (tid >> 6) * 4;
    const float b = ldp(bias, f, flag);
    float a0 = b, a1 = b, a2 = b, a3 = b;
    #pragma unroll
    for (int k = 0; k < 64; ++k) {
        const float wk = Wf[k * 64 + f];
        a0 = fmaf(S[(r0 + 0) * 64 + k], wk, a0);
        a1 = fmaf(S[(r0 + 1) * 64 + k], wk, a1);
        a2 = fmaf(S[(r0 + 2) * 64 + k], wk, a2);
        a3 = fmaf(S[(r0 + 3) * 64 + k], wk, a3);
    }
    dst[(size_t)(rbase + r0 + 0) * 64 + f] = a0;
    dst[(size_t)(rbase + r0 + 1) * 64 + f] = a1;
    dst[(size_t)(rbase + r0 + 2) * 64 + f] = a2;
    dst[(size_t)(rbase + r0 + 3) * 64 + f] = a3;

    shs[tid] = (double)a0 + (double)a1 + (double)a2 + (double)a3;
    shq[tid] = (double)a0 * a0 + (double)a1 * a1
             + (double)a2 * a2 + (double)a3 * a3;
    __syncthreads();
    if (tid < 64) {
        double S2 = shs[tid] + shs[64 + tid] + shs[128 + tid] + shs[192 + tid];
        double Q2 = shq[tid] + shq[64 + tid] + shq[128 + tid] + shq[192 + tid];
        double* so = statsOut + (blockIdx.x & (NSLOT - 1)) * 128;
        atomicAdd(&so[tid], S2);
        atomicAdd(&so[64 + tid], Q2);
    }
}

// ---------------------------------------------------------------------------
// K4: fused spmm + mm1a at 8 rows/block (2048 blocks) — double the gather TLP
// vs a 16-row version (R5 lesson: the gather is latency-bound, needs waves).
//  S[ri,:] = invdeg * sum_k relu(BN(H0[cols,:]))  (outer BN on the fly)
//  A1 = S @ W1_1 + b1_1 -> global, + fused column stats.
__global__ __launch_bounds__(256) void k_spmm_mm(
    const float* __restrict__ t, const double* __restrict__ statsIn,
    const void* __restrict__ g, const void* __restrict__ be,
    const u16* __restrict__ cols, const int* __restrict__ cnt,
    const float* __restrict__ invdeg,
    const void* __restrict__ W, const void* __restrict__ bias,
    float* __restrict__ dstA, double* __restrict__ statsOut,
    const int* __restrict__ flagp)
{
    __shared__ float Wf[64 * 64];
    __shared__ float S[8 * 64];
    __shared__ float ac[128];
    __shared__ double shs[256];
    __shared__ double shq[256];
    const int tid = threadIdx.x;
    const int wave = tid >> 6, lane = tid & 63;
    const int flag = *flagp;
    if (tid < 64) {
        double ss = 0.0, qq = 0.0;
        #pragma unroll
        for (int s2 = 0; s2 < NSLOT; ++s2) {
            ss += statsIn[s2 * 128 + tid];
            qq += statsIn[s2 * 128 + 64 + tid];
        }
        double m = ss * (1.0 / N_NODES);
        double v = qq * (1.0 / N_NODES) - m * m;
        float A = ldp(g, tid, flag) / sqrtf((float)v + BN_EPS);
        ac[tid] = A;
        ac[64 + tid] = ldp(be, tid, flag) - (float)m * A;
    }
    for (int i = tid; i < 64 * 64; i += 256) Wf[i] = ldp(W, i, flag);
    __syncthreads();

    const int rbase = blockIdx.x * 8;
    {
        const float A = ac[lane], C = ac[64 + lane];
        for (int ri = 0; ri < 2; ++ri) {
            const int row = rbase + wave * 2 + ri;
            const u16* __restrict__ crow = cols + (size_t)row * MAXD;
            const int n = cnt[row];
            float acc = 0.f;
            int k = 0;
            for (; k + 4 <= n; k += 4) {
                ushort4 j4 = *(const ushort4*)&crow[k];
                float v0 = t[(size_t)j4.x * HD + lane];
                float v1 = t[(size_t)j4.y * HD + lane];
                float v2 = t[(size_t)j4.z * HD + lane];
                float v3 = t[(size_t)j4.w * HD + lane];
                acc += fmaxf(fmaf(A, v0, C), 0.f);
                acc += fmaxf(fmaf(A, v1, C), 0.f);
                acc += fmaxf(fmaf(A, v2, C), 0.f);
                acc += fmaxf(fmaf(A, v3, C), 0.f);
            }
            for (; k < n; ++k) {
                float vv = t[(size_t)crow[k] * HD + lane];
                acc += fmaxf(fmaf(A, vv, C), 0.f);
            }
            S[(wave * 2 + ri) * 64 + lane] = acc * invdeg[row];
        }
    }
    __syncthreads();

    // mm: 8 rows x 64 features -> 2 outputs/thread
    const int f = tid & 63, r0 = (tid >> 6) * 2;
    const float b = ldp(bias, f, flag);
    float a0 = b, a1 = b;
    #pragma unroll
    for (int k = 0; k < 64; ++k) {
        const float wk = Wf[k * 64 + f];
        a0 = fmaf(S[(r0 + 0) * 64 + k], wk, a0);
        a1 = fmaf(S[(r0 + 1) * 64 + k], wk, a1);
    }
    dstA[(size_t)(rbase + r0 + 0) * 64 + f] = a0;
    dstA[(size_t)(rbase + r0 + 1) * 64 + f] = a1;

    shs[tid] = (double)a0 + (double)a1;
    shq[tid] = (double)a0 * a0 + (double)a1 * a1;
    __syncthreads();
    if (tid < 64) {
        double S2 = shs[tid] + shs[64 + tid] + shs[128 + tid] + shs[192 + tid];
        double Q2 = shq[tid] + shq[64 + tid] + shq[128 + tid] + shq[192 + tid];
        double* so = statsOut + (blockIdx.x & (NSLOT - 1)) * 128;
        atomicAdd(&so[tid], S2);
        atomicAdd(&so[64 + tid], Q2);
    }
}

// ---------------------------------------------------------------------------
// K6: fused final BN+relu AND graph pooling (two block roles, one launch).
// Blocks [0,256):   out_nodes = relu(A*H1 + C)   (elementwise, float4)
// Blocks [256,384): out_pool[g,:] = sum_j gp[g,j] * relu(A*H1[j,:]+C)
__global__ __launch_bounds__(1024) void k_bnrelu_pool(
    const float* __restrict__ P, const double* __restrict__ statsIn,
    const void* __restrict__ g, const void* __restrict__ be,
    const void* __restrict__ gpv, float* __restrict__ out_nodes,
    float* __restrict__ out_pool, const int* __restrict__ flagp)
{
    __shared__ float ac[128];
    __shared__ float red[16 * 64];
    const int tid = threadIdx.x;
    const int flag = *flagp;
    if (tid < 64) {
        double ss = 0.0, qq = 0.0;
        #pragma unroll
        for (int s2 = 0; s2 < NSLOT; ++s2) {
            ss += statsIn[s2 * 128 + tid];
            qq += statsIn[s2 * 128 + 64 + tid];
        }
        double m = ss * (1.0 / N_NODES);
        double v = qq * (1.0 / N_NODES) - m * m;
        float A = ldp(g, tid, flag) / sqrtf((float)v + BN_EPS);
        ac[tid] = A;
        ac[64 + tid] = ldp(be, tid, flag) - (float)m * A;
    }
    __syncthreads();

    if (blockIdx.x < 256) {
        const size_t idx = ((size_t)blockIdx.x * 1024 + tid) * 4;
        const int f0 = (int)(idx & 63);
        float4 t = *(const float4*)&P[idx];
        const float4 A4 = *(const float4*)&ac[f0];
        const float4 C4 = *(const float4*)&ac[64 + f0];
        float4 r;
        r.x = fmaxf(fmaf(A4.x, t.x, C4.x), 0.f);
        r.y = fmaxf(fmaf(A4.y, t.y, C4.y), 0.f);
        r.z = fmaxf(fmaf(A4.z, t.z, C4.z), 0.f);
        r.w = fmaxf(fmaf(A4.w, t.w, C4.w), 0.f);
        *(float4*)&out_nodes[idx] = r;
    } else {
        const int gidx = blockIdx.x - 256;
        const int wave = tid >> 6, lane = tid & 63;
        const float A = ac[lane], C = ac[64 + lane];
        float acc = 0.f;
        const int jb0 = wave * (N_NODES / 16);
        if (flag) {
            const float* __restrict__ grow =
                (const float*)gpv + (size_t)gidx * N_NODES;
            for (int jb = jb0; jb < jb0 + N_NODES / 16; jb += 4) {
                float4 raw = *(const float4*)(grow + jb);
                if (raw.x != 0.f)
                    acc += raw.x * fmaxf(fmaf(A, P[(size_t)(jb + 0) * HD + lane], C), 0.f);
                if (raw.y != 0.f)
                    acc += raw.y * fmaxf(fmaf(A, P[(size_t)(jb + 1) * HD + lane], C), 0.f);
                if (raw.z != 0.f)
                    acc += raw.z * fmaxf(fmaf(A, P[(size_t)(jb + 2) * HD + lane], C), 0.f);
                if (raw.w != 0.f)
                    acc += raw.w * fmaxf(fmaf(A, P[(size_t)(jb + 3) * HD + lane], C), 0.f);
            }
        } else {
            const u16* __restrict__ grow =
                (const u16*)gpv + (size_t)gidx * N_NODES;
            for (int jb = jb0; jb < jb0 + N_NODES / 16; jb += 8) {
                uint4 raw = *(const uint4*)(grow + jb);
                const u32 w[4] = {raw.x, raw.y, raw.z, raw.w};
                #pragma unroll
                for (int e = 0; e < 8; ++e) {
                    u16 u = (u16)(w[e >> 1] >> ((e & 1) * 16));
                    if (u)
                        acc += bf2f(u) * fmaxf(fmaf(A, P[(size_t)(jb + e) * HD + lane], C), 0.f);
                }
            }
        }
        red[wave * 64 + lane] = acc;
        __syncthreads();
        if (wave == 0) {
            float s = 0.f;
            #pragma unroll
            for (int w2 = 0; w2 < 16; ++w2) s += red[w2 * 64 + lane];
            out_pool[gidx * 64 + lane] = s;
        }
    }
}

// ---------------------------------------------------------------------------
extern "C" void kernel_launch(void* const* d_in, const int* in_sizes, int n_in,
                              void* d_out, int out_size, void* d_ws, size_t ws_size,
                              hipStream_t stream)
{
    const void* x    = d_in[0];
    const void* adj  = d_in[1];
    const void* gp   = d_in[2];
    const void* W1_0 = d_in[3];
    const void* b1_0 = d_in[4];
    const void* g1_0 = d_in[5];
    const void* be1_0= d_in[6];
    const void* W2_0 = d_in[7];
    const void* b2_0 = d_in[8];
    const void* g_0  = d_in[9];
    const void* be_0 = d_in[10];
    const void* W1_1 = d_in[11];
    const void* b1_1 = d_in[12];
    const void* g1_1 = d_in[13];
    const void* be1_1= d_in[14];
    const void* W2_1 = d_in[15];
    const void* b2_1 = d_in[16];
    const void* g_1  = d_in[17];
    const void* be_1 = d_in[18];

    char* ws = (char*)d_ws;
    float*  P0     = (float*) (ws);                        // 4 MB (gather out)
    float*  Abuf   = (float*) (ws + (4u  << 20));          // 4 MB (A0/A1)
    float*  H0     = (float*) (ws + (8u  << 20));          // 4 MB
    float*  H1     = (float*) (ws + (12u << 20));          // 4 MB
    u16*    cols   = (u16*)   (ws + (16u << 20));          // 6 MB
    int*    cnt    = (int*)   (ws + (22u << 20));          // 64 KB
    float*  invdeg = (float*) (ws + (22u << 20) + 65536);  // 64 KB
    double* sd     = (double*)(ws + (22u << 20) + 131072); // 8192 f64 (64 KB)
    int*    flag   = (int*)   (ws + (22u << 20) + 196608);

    // Outputs are float32.
    float* out_pool  = (float*)d_out;            // [128,64]
    float* out_nodes = (float*)d_out + GG * HD;  // [16384,64]

    // stats arena: 4 groups x NSLOT(16) slots x 128 doubles
    double* st0 = sd + 0 * STG;   // stats(A0)
    double* st1 = sd + 1 * STG;   // stats(H0)
    double* st2 = sd + 2 * STG;   // stats(A1)
    double* st3 = sd + 3 * STG;   // stats(H1)

    // K1: lean scan + gather (max occupancy; adj stream at HBM floor)
    k_scan_gather<<<N_NODES / 4, 256, 0, stream>>>(
        adj, x, cols, cnt, invdeg, P0, sd, flag);
    // K2: A0 = P0 @ W1_0 + b1_0 (+ stats A0)
    k_mm<false><<<N_NODES / 16, 256, 0, stream>>>(
        P0, nullptr, nullptr, nullptr, W1_0, b1_0, Abuf, st0, flag);
    // K3: H0 = relu(BN(A0)) @ W2_0 + b2_0 (+ stats H0)
    k_mm<true><<<N_NODES / 16, 256, 0, stream>>>(
        Abuf, st0, g1_0, be1_0, W2_0, b2_0, H0, st1, flag);
    // K4: spmm(BN(H0)+relu on the fly) + mm1a (+ stats A1), 8 rows/block
    k_spmm_mm<<<N_NODES / 8, 256, 0, stream>>>(
        H0, st1, g_0, be_0, cols, cnt, invdeg, W1_1, b1_1, Abuf, st2, flag);
    // K5: H1 = relu(BN(A1)) @ W2_1 + b2_1 (+ stats H1)
    k_mm<true><<<N_NODES / 16, 256, 0, stream>>>(
        Abuf, st2, g1_1, be1_1, W2_1, b2_1, H1, st3, flag);
    // K6: final BN+relu -> out_nodes, graph pool -> out_pool
    k_bnrelu_pool<<<256 + GG, 1024, 0, stream>>>(
        H1, st3, g_1, be_1, gp, out_nodes, out_pool, flag);
}

// Round 7
// 1542.032 us; speedup vs baseline: 1.0255x; 1.0255x over previous
//
#include <hip/hip_runtime.h>
#include <hip/hip_bf16.h>
#include <stdint.h>

#define N_NODES 16384
#define GG      128
#define HD      64
#define MAXD    192
#define BN_EPS  1e-5f
#define NSLOT   16             // stats contention slots (64 serialized RMWs/address)
#define STG     (NSLOT * 128)  // doubles per stats group (group stride)

typedef unsigned short u16;
typedef unsigned int   u32;
typedef unsigned long long u64;
typedef u32 u32x4 __attribute__((ext_vector_type(4)));  // nontemporal-compatible

__device__ __forceinline__ float bf2f(u16 u) {
    union { u32 i; float f; } c; c.i = ((u32)u) << 16; return c.f;
}
// param load in native dtype (flag: 1=f32, 0=bf16)
__device__ __forceinline__ float ldp(const void* p, int i, int flag) {
    return flag ? ((const float*)p)[i] : bf2f(((const u16*)p)[i]);
}

// ---------------------------------------------------------------------------
// K1: LEAN fused scan+gather — best-measured config (R2). Do NOT fatten this
// kernel (R5 lesson): it must run at max occupancy to keep the nontemporal
// adj stream at the HBM floor.
//  phase 1: streaming ballot-compaction scan of adj row -> cols in LDS
//  phase 2: cols -> global (for K4's spmm), gather pooled -> P0
// Housekeeping: zero 4*STG stats arena, publish dtype flag from adj[0][0]
// (f32 -> word0 low16 == 0; bf16 -> low16 = 0x3F80 != 0).
__global__ __launch_bounds__(256) void k_scan_gather(
    const void* __restrict__ adjv, const void* __restrict__ xv,
    u16* __restrict__ cols, int* __restrict__ cnt,
    float* __restrict__ invdeg, float* __restrict__ pooled,
    double* __restrict__ statsD, int* __restrict__ flagp)
{
    __shared__ __align__(16) u16 sc[4][MAXD];
    const int wave = threadIdx.x >> 6, lane = threadIdx.x & 63;
    const int row = blockIdx.x * 4 + wave;
    const u32 w0 = *(const u32*)adjv;                      // scalar, cached
    const int flag = ((w0 & 0xFFFFu) == 0) ? 1 : 0;
    const u64 ltmask = ((1ull << lane) - 1ull);

    // housekeeping
    const int gid = blockIdx.x * 256 + threadIdx.x;
    if (gid < 4 * STG) statsD[gid] = 0.0;
    if (gid == 0) *flagp = flag;

    u16* __restrict__ srow = sc[wave];
    int base = 0;
    if (flag) {  // ---- f32: u32x4 = 4 elements, 256 elems/wave-chunk ----
        const u32x4* __restrict__ arow =
            (const u32x4*)((const u32*)adjv + (size_t)row * N_NODES) + lane;
        u32x4 p0 = __builtin_nontemporal_load(arow);
        u32x4 p1 = __builtin_nontemporal_load(arow + 64);
        for (int c = 0; c < N_NODES; c += 256) {
            u32x4 raw = p0;
            p0 = p1;
            if (c + 512 < N_NODES)
                p1 = __builtin_nontemporal_load(arow + (c + 512) / 4);
            #pragma unroll
            for (int e = 0; e < 4; ++e) {
                u32 w = raw[e];
                u64 m = __ballot(w != 0);
                if (m) {
                    if (w) {
                        int p = base + __popcll(m & ltmask);
                        if (p < MAXD) srow[p] = (u16)(c + lane * 4 + e);
                    }
                    base += __popcll(m);
                }
            }
        }
    } else {     // ---- bf16: u32x4 = 8 elements, 512 elems/wave-chunk ----
        const u32x4* __restrict__ arow =
            (const u32x4*)((const u16*)adjv + (size_t)row * N_NODES) + lane;
        u32x4 p0 = __builtin_nontemporal_load(arow);
        u32x4 p1 = __builtin_nontemporal_load(arow + 64);
        for (int c = 0; c < N_NODES; c += 512) {
            u32x4 raw = p0;
            p0 = p1;
            if (c + 1024 < N_NODES)
                p1 = __builtin_nontemporal_load(arow + (c + 1024) / 8);
            #pragma unroll
            for (int e = 0; e < 8; ++e) {
                u16 u = (u16)(raw[e >> 1] >> ((e & 1) * 16));
                u64 m = __ballot(u != 0);
                if (m) {
                    if (u) {
                        int p = base + __popcll(m & ltmask);
                        if (p < MAXD) srow[p] = (u16)(c + lane * 8 + e);
                    }
                    base += __popcll(m);
                }
            }
        }
    }
    const int n = (base < MAXD) ? base : MAXD;
    if (lane == 0) cnt[row] = n;
    __syncthreads();   // LDS cols visible

    // stream cols to global (garbage > n ok, reads bounded by cnt)
    {
        u32* __restrict__ crow32 = (u32*)(cols + (size_t)row * MAXD);
        const u32* __restrict__ s32 = (const u32*)srow;
        #pragma unroll
        for (int t = lane; t < MAXD / 2; t += 64) crow32[t] = s32[t];
    }

    // gather (cols from LDS are wave-uniform broadcasts)
    float acc = 0.f;
    int k = 0;
    if (flag) {
        const float* __restrict__ x = (const float*)xv;
        for (; k + 4 <= n; k += 4) {
            ushort4 j4 = *(const ushort4*)&srow[k];
            float v0 = x[(size_t)j4.x * HD + lane];
            float v1 = x[(size_t)j4.y * HD + lane];
            float v2 = x[(size_t)j4.z * HD + lane];
            float v3 = x[(size_t)j4.w * HD + lane];
            acc += (v0 + v1) + (v2 + v3);
        }
        for (; k < n; ++k) acc += x[(size_t)srow[k] * HD + lane];
    } else {
        const u16* __restrict__ x = (const u16*)xv;
        for (; k + 4 <= n; k += 4) {
            ushort4 j4 = *(const ushort4*)&srow[k];
            float v0 = bf2f(x[(size_t)j4.x * HD + lane]);
            float v1 = bf2f(x[(size_t)j4.y * HD + lane]);
            float v2 = bf2f(x[(size_t)j4.z * HD + lane]);
            float v3 = bf2f(x[(size_t)j4.w * HD + lane]);
            acc += (v0 + v1) + (v2 + v3);
        }
        for (; k < n; ++k) acc += bf2f(x[(size_t)srow[k] * HD + lane]);
    }
    float inv = 1.f / (float)n;                     // n >= 1 (self-loop)
    pooled[(size_t)row * HD + lane] = acc * inv;
    if (lane == 0) invdeg[row] = inv;
}

// ---------------------------------------------------------------------------
// dst[N,64] = f(src)[N,64] @ W[64,64] + bias, PLUS fused column stats of dst
// into the NSLOT-slot statsOut group. f = identity (AFFINE=false) or
// per-feature relu(A*v+C) (AFFINE=true) with A,C from statsIn.
// 16 rows/block (1024 blocks); each thread owns 4 rows of one output feature.
template<bool AFFINE>
__global__ __launch_bounds__(256) void k_mm(
    const float* __restrict__ src, const double* __restrict__ statsIn,
    const void* __restrict__ g, const void* __restrict__ be,
    const void* __restrict__ W, const void* __restrict__ bias,
    float* __restrict__ dst, double* __restrict__ statsOut,
    const int* __restrict__ flagp)
{
    __shared__ float Wf[64 * 64];
    __shared__ float S[16 * 64];
    __shared__ float ac[128];
    __shared__ double shs[256];
    __shared__ double shq[256];
    const int tid = threadIdx.x;
    const int flag = *flagp;
    if (AFFINE) {
        if (tid < 64) {
            double ss = 0.0, qq = 0.0;
            #pragma unroll
            for (int s2 = 0; s2 < NSLOT; ++s2) {
                ss += statsIn[s2 * 128 + tid];
                qq += statsIn[s2 * 128 + 64 + tid];
            }
            double m = ss * (1.0 / N_NODES);
            double v = qq * (1.0 / N_NODES) - m * m;
            float A = ldp(g, tid, flag) / sqrtf((float)v + BN_EPS);
            ac[tid] = A;
            ac[64 + tid] = ldp(be, tid, flag) - (float)m * A;
        }
        __syncthreads();
    }
    for (int i = tid; i < 64 * 64; i += 256) Wf[i] = ldp(W, i, flag);
    const int rbase = blockIdx.x * 16;
    {
        float4 v = *(const float4*)&src[(size_t)rbase * 64 + tid * 4];
        if (AFFINE) {
            const int f0 = (tid * 4) & 63;
            v.x = fmaxf(fmaf(ac[f0 + 0], v.x, ac[64 + f0 + 0]), 0.f);
            v.y = fmaxf(fmaf(ac[f0 + 1], v.y, ac[64 + f0 + 1]), 0.f);
            v.z = fmaxf(fmaf(ac[f0 + 2], v.z, ac[64 + f0 + 2]), 0.f);
            v.w = fmaxf(fmaf(ac[f0 + 3], v.w, ac[64 + f0 + 3]), 0.f);
        }
        *(float4*)&S[tid * 4] = v;
    }
    __syncthreads();
    const int f = tid & 63, r0 = (tid >> 6) * 4;
    const float b = ldp(bias, f, flag);
    float a0 = b, a1 = b, a2 = b, a3 = b;
    #pragma unroll
    for (int k = 0; k < 64; ++k) {
        const float wk = Wf[k * 64 + f];
        a0 = fmaf(S[(r0 + 0) * 64 + k], wk, a0);
        a1 = fmaf(S[(r0 + 1) * 64 + k], wk, a1);
        a2 = fmaf(S[(r0 + 2) * 64 + k], wk, a2);
        a3 = fmaf(S[(r0 + 3) * 64 + k], wk, a3);
    }
    dst[(size_t)(rbase + r0 + 0) * 64 + f] = a0;
    dst[(size_t)(rbase + r0 + 1) * 64 + f] = a1;
    dst[(size_t)(rbase + r0 + 2) * 64 + f] = a2;
    dst[(size_t)(rbase + r0 + 3) * 64 + f] = a3;

    // fused column stats of this block's 16x64 tile
    shs[tid] = (double)a0 + (double)a1 + (double)a2 + (double)a3;
    shq[tid] = (double)a0 * a0 + (double)a1 * a1
             + (double)a2 * a2 + (double)a3 * a3;
    __syncthreads();
    if (tid < 64) {
        double S2 = shs[tid] + shs[64 + tid] + shs[128 + tid] + shs[192 + tid];
        double Q2 = shq[tid] + shq[64 + tid] + shq[128 + tid] + shq[192 + tid];
        double* so = statsOut + (blockIdx.x & (NSLOT - 1)) * 128;
        atomicAdd(&so[tid], S2);
        atomicAdd(&so[64 + tid], Q2);
    }
}

// ---------------------------------------------------------------------------
// K4: spmm, LEAN (R2 config: 4 rows/block, 4096 blocks, no Wf stage — the
// gather is latency-bound and wants max TLP; R5/R6 fusions both regressed).
// pooled[i,:] = invdeg[i] * sum_k relu(A*t[cols[i,k],:]+C)
__global__ __launch_bounds__(256) void k_spmm(
    const float* __restrict__ t, const double* __restrict__ statsIn,
    const void* __restrict__ g, const void* __restrict__ be,
    const u16* __restrict__ cols, const int* __restrict__ cnt,
    const float* __restrict__ invdeg, float* __restrict__ pooled,
    const int* __restrict__ flagp)
{
    __shared__ float ac[128];
    const int tid = threadIdx.x;
    const int wave = tid >> 6, lane = tid & 63;
    const int row = blockIdx.x * 4 + wave;
    const int flag = *flagp;
    if (tid < 64) {
        double ss = 0.0, qq = 0.0;
        #pragma unroll
        for (int s2 = 0; s2 < NSLOT; ++s2) {
            ss += statsIn[s2 * 128 + tid];
            qq += statsIn[s2 * 128 + 64 + tid];
        }
        double m = ss * (1.0 / N_NODES);
        double v = qq * (1.0 / N_NODES) - m * m;
        float A = ldp(g, tid, flag) / sqrtf((float)v + BN_EPS);
        ac[tid] = A;
        ac[64 + tid] = ldp(be, tid, flag) - (float)m * A;
    }
    __syncthreads();
    const float A = ac[lane], C = ac[64 + lane];

    const u16* __restrict__ crow = cols + (size_t)row * MAXD;
    const int n = cnt[row];
    float acc = 0.f;
    int k = 0;
    for (; k + 4 <= n; k += 4) {
        ushort4 j4 = *(const ushort4*)&crow[k];
        float v0 = t[(size_t)j4.x * HD + lane];
        float v1 = t[(size_t)j4.y * HD + lane];
        float v2 = t[(size_t)j4.z * HD + lane];
        float v3 = t[(size_t)j4.w * HD + lane];
        acc += fmaxf(fmaf(A, v0, C), 0.f);
        acc += fmaxf(fmaf(A, v1, C), 0.f);
        acc += fmaxf(fmaf(A, v2, C), 0.f);
        acc += fmaxf(fmaf(A, v3, C), 0.f);
    }
    for (; k < n; ++k) {
        float vv = t[(size_t)crow[k] * HD + lane];
        acc += fmaxf(fmaf(A, vv, C), 0.f);
    }
    pooled[(size_t)row * HD + lane] = acc * invdeg[row];
}

// ---------------------------------------------------------------------------
// K7: fused final BN+relu AND graph pooling (two block roles, one launch).
// Blocks [0,256):   out_nodes = relu(A*P + C)   (elementwise, float4)
// Blocks [256,384): out_pool[g,:] = sum_j gp[g,j] * relu(A*P[j,:]+C)
__global__ __launch_bounds__(1024) void k_bnrelu_pool(
    const float* __restrict__ P, const double* __restrict__ statsIn,
    const void* __restrict__ g, const void* __restrict__ be,
    const void* __restrict__ gpv, float* __restrict__ out_nodes,
    float* __restrict__ out_pool, const int* __restrict__ flagp)
{
    __shared__ float ac[128];
    __shared__ float red[16 * 64];
    const int tid = threadIdx.x;
    const int flag = *flagp;
    if (tid < 64) {
        double ss = 0.0, qq = 0.0;
        #pragma unroll
        for (int s2 = 0; s2 < NSLOT; ++s2) {
            ss += statsIn[s2 * 128 + tid];
            qq += statsIn[s2 * 128 + 64 + tid];
        }
        double m = ss * (1.0 / N_NODES);
        double v = qq * (1.0 / N_NODES) - m * m;
        float A = ldp(g, tid, flag) / sqrtf((float)v + BN_EPS);
        ac[tid] = A;
        ac[64 + tid] = ldp(be, tid, flag) - (float)m * A;
    }
    __syncthreads();

    if (blockIdx.x < 256) {
        const size_t idx = ((size_t)blockIdx.x * 1024 + tid) * 4;
        const int f0 = (int)(idx & 63);
        float4 t = *(const float4*)&P[idx];
        const float4 A4 = *(const float4*)&ac[f0];
        const float4 C4 = *(const float4*)&ac[64 + f0];
        float4 r;
        r.x = fmaxf(fmaf(A4.x, t.x, C4.x), 0.f);
        r.y = fmaxf(fmaf(A4.y, t.y, C4.y), 0.f);
        r.z = fmaxf(fmaf(A4.z, t.z, C4.z), 0.f);
        r.w = fmaxf(fmaf(A4.w, t.w, C4.w), 0.f);
        *(float4*)&out_nodes[idx] = r;
    } else {
        const int gidx = blockIdx.x - 256;
        const int wave = tid >> 6, lane = tid & 63;
        const float A = ac[lane], C = ac[64 + lane];
        float acc = 0.f;
        const int jb0 = wave * (N_NODES / 16);
        if (flag) {
            const float* __restrict__ grow =
                (const float*)gpv + (size_t)gidx * N_NODES;
            for (int jb = jb0; jb < jb0 + N_NODES / 16; jb += 4) {
                float4 raw = *(const float4*)(grow + jb);
                if (raw.x != 0.f)
                    acc += raw.x * fmaxf(fmaf(A, P[(size_t)(jb + 0) * HD + lane], C), 0.f);
                if (raw.y != 0.f)
                    acc += raw.y * fmaxf(fmaf(A, P[(size_t)(jb + 1) * HD + lane], C), 0.f);
                if (raw.z != 0.f)
                    acc += raw.z * fmaxf(fmaf(A, P[(size_t)(jb + 2) * HD + lane], C), 0.f);
                if (raw.w != 0.f)
                    acc += raw.w * fmaxf(fmaf(A, P[(size_t)(jb + 3) * HD + lane], C), 0.f);
            }
        } else {
            const u16* __restrict__ grow =
                (const u16*)gpv + (size_t)gidx * N_NODES;
            for (int jb = jb0; jb < jb0 + N_NODES / 16; jb += 8) {
                uint4 raw = *(const uint4*)(grow + jb);
                const u32 w[4] = {raw.x, raw.y, raw.z, raw.w};
                #pragma unroll
                for (int e = 0; e < 8; ++e) {
                    u16 u = (u16)(w[e >> 1] >> ((e & 1) * 16));
                    if (u)
                        acc += bf2f(u) * fmaxf(fmaf(A, P[(size_t)(jb + e) * HD + lane], C), 0.f);
                }
            }
        }
        red[wave * 64 + lane] = acc;
        __syncthreads();
        if (wave == 0) {
            float s = 0.f;
            #pragma unroll
            for (int w2 = 0; w2 < 16; ++w2) s += red[w2 * 64 + lane];
            out_pool[gidx * 64 + lane] = s;
        }
    }
}

// ---------------------------------------------------------------------------
extern "C" void kernel_launch(void* const* d_in, const int* in_sizes, int n_in,
                              void* d_out, int out_size, void* d_ws, size_t ws_size,
                              hipStream_t stream)
{
    const void* x    = d_in[0];
    const void* adj  = d_in[1];
    const void* gp   = d_in[2];
    const void* W1_0 = d_in[3];
    const void* b1_0 = d_in[4];
    const void* g1_0 = d_in[5];
    const void* be1_0= d_in[6];
    const void* W2_0 = d_in[7];
    const void* b2_0 = d_in[8];
    const void* g_0  = d_in[9];
    const void* be_0 = d_in[10];
    const void* W1_1 = d_in[11];
    const void* b1_1 = d_in[12];
    const void* g1_1 = d_in[13];
    const void* be1_1= d_in[14];
    const void* W2_1 = d_in[15];
    const void* b2_1 = d_in[16];
    const void* g_1  = d_in[17];
    const void* be_1 = d_in[18];

    char* ws = (char*)d_ws;
    float*  P      = (float*) (ws);                        // 4 MB
    float*  A      = (float*) (ws + (4u  << 20));          // 4 MB
    float*  B      = (float*) (ws + (8u  << 20));          // 4 MB
    u16*    cols   = (u16*)   (ws + (12u << 20));          // 6 MB
    int*    cnt    = (int*)   (ws + (18u << 20));          // 64 KB
    float*  invdeg = (float*) (ws + (18u << 20) + 65536);  // 64 KB
    double* sd     = (double*)(ws + (18u << 20) + 131072); // 8192 f64 (64 KB)
    int*    flag   = (int*)   (ws + (18u << 20) + 196608);

    // Outputs are float32.
    float* out_pool  = (float*)d_out;            // [128,64]
    float* out_nodes = (float*)d_out + GG * HD;  // [16384,64]

    // stats arena: 4 groups x NSLOT(16) slots x 128 doubles
    double* st0 = sd + 0 * STG;   // stats(A0)
    double* st1 = sd + 1 * STG;   // stats(H0)
    double* st2 = sd + 2 * STG;   // stats(A1)
    double* st3 = sd + 3 * STG;   // stats(H1)

    k_scan_gather<<<N_NODES / 4, 256, 0, stream>>>(adj, x, cols, cnt,
                                                   invdeg, P, sd, flag);

    // ----- layer 0 -----
    k_mm<false><<<N_NODES / 16, 256, 0, stream>>>(P, nullptr, nullptr, nullptr,
                                                  W1_0, b1_0, A, st0, flag);
    k_mm<true><<<N_NODES / 16, 256, 0, stream>>>(A, st0, g1_0, be1_0,
                                                 W2_0, b2_0, P, st1, flag);
    // layer-0 outer BN+relu fused into the layer-1 aggregation gather:
    k_spmm<<<N_NODES / 4, 256, 0, stream>>>(P, st1, g_0, be_0,
                                            cols, cnt, invdeg, B, flag);
    // ----- layer 1 -----
    k_mm<false><<<N_NODES / 16, 256, 0, stream>>>(B, nullptr, nullptr, nullptr,
                                                  W1_1, b1_1, A, st2, flag);
    k_mm<true><<<N_NODES / 16, 256, 0, stream>>>(A, st2, g1_1, be1_1,
                                                 W2_1, b2_1, P, st3, flag);
    // final BN+relu (-> out_nodes) and graph pooling (-> out_pool), fused:
    k_bnrelu_pool<<<256 + GG, 1024, 0, stream>>>(P, st3, g_1, be_1, gp,
                                                 out_nodes, out_pool, flag);
}